// Round 1
// baseline (491.568 us; speedup 1.0000x reference)
//
#include <hip/hip_runtime.h>

#define N_NODES 50000
#define N_EDGES 800000
#define HDIM 128
#define ODIM 64
#define NLAYER 3
#define NGRAPH 512
#define BN_EPS 1e-5f
#define NCHUNK 4
#define CROWS 12500      // src rows per chunk (3.2 MB bf16 -> fits 4 MB XCD L2)
#define CCAP 24          // per-(node,chunk) capacity; deg_c ~ Poisson(4), P(>=25)~1e-12
#define NBLK 782         // mlp grid: ceil(50000/64)
#define GBLK 782         // gml grid: ceil(50000/64)
#define HPITCH 136
#define TPITCH 136
#define NSLICE 98        // ceil(782/8): XCD-mate prefetch slices per chunk
#define SLICE_ROWS 128   // 98*128 = 12544 >= 12500

// k_prep block-range partition
#define SCAT_BLK 782            // 800000 edges / 4 per thread / 256
#define CVT_BLK 6250            // 1.6M float4
#define CVTW_BLK 481            // 122880 weight elems + sentinel zeros

typedef __attribute__((ext_vector_type(8))) short short8;
typedef __attribute__((ext_vector_type(8))) unsigned short ushort8;
typedef __attribute__((ext_vector_type(4))) float floatx4;

static __device__ __forceinline__ unsigned short f2bf(float f) {
    union { float f; unsigned int u; } v; v.f = f;
    unsigned int r = v.u + 0x7FFFu + ((v.u >> 16) & 1u);
    return (unsigned short)(r >> 16);
}
static __device__ __forceinline__ float bf2f(unsigned short s) {
    union { unsigned int u; float f; } v; v.u = ((unsigned int)s) << 16;
    return v.f;
}

// ---- fused prep: chunked scatter (4 edges/thread) + cvt + cvtW + sentinels ----

__global__ __launch_bounds__(256) void k_prep(
    const int* __restrict__ src, const int* __restrict__ dst,
    int* __restrict__ cnt, unsigned short* __restrict__ colidx,
    const float* __restrict__ x, unsigned short* __restrict__ xb,
    const float* __restrict__ W1, const float* __restrict__ W2,
    const float* __restrict__ hW1, const float* __restrict__ hW2,
    unsigned short* __restrict__ wtb, unsigned short* __restrict__ xa2)
{
    int b = blockIdx.x;
    int tid = threadIdx.x;
    if (b < SCAT_BLK) {
        int base = (b * 256 + tid) * 4;
        if (base < N_EDGES) {
            int4 s4 = *(const int4*)(src + base);
            int4 d4 = *(const int4*)(dst + base);
            int c0 = s4.x / CROWS, c1 = s4.y / CROWS, c2 = s4.z / CROWS, c3 = s4.w / CROWS;
            int p0 = atomicAdd(&cnt[d4.x * NCHUNK + c0], 1);
            int p1 = atomicAdd(&cnt[d4.y * NCHUNK + c1], 1);
            int p2 = atomicAdd(&cnt[d4.z * NCHUNK + c2], 1);
            int p3 = atomicAdd(&cnt[d4.w * NCHUNK + c3], 1);
            if (p0 < CCAP) colidx[((size_t)d4.x * NCHUNK + c0) * CCAP + p0] = (unsigned short)s4.x;
            if (p1 < CCAP) colidx[((size_t)d4.y * NCHUNK + c1) * CCAP + p1] = (unsigned short)s4.y;
            if (p2 < CCAP) colidx[((size_t)d4.z * NCHUNK + c2) * CCAP + p2] = (unsigned short)s4.z;
            if (p3 < CCAP) colidx[((size_t)d4.w * NCHUNK + c3) * CCAP + p3] = (unsigned short)s4.w;
        }
    } else if (b < SCAT_BLK + CVT_BLK) {
        int i = (b - SCAT_BLK) * 256 + tid;
        if (i < N_NODES * HDIM / 4) {
            float4 v = ((const float4*)x)[i];
            ushort4 o = make_ushort4(f2bf(v.x), f2bf(v.y), f2bf(v.z), f2bf(v.w));
            ((ushort4*)xb)[i] = o;
        }
    } else {
        int idx = (b - SCAT_BLK - CVT_BLK) * 256 + tid;
        if (idx < 6 * HDIM * HDIM) {
            // conv weights: mat 2l=W1[l], 2l+1=W2[l]; [k][n] -> [n][k] bf16
            int mat = idx >> 14;
            int rem = idx & 16383;
            int k = rem >> 7, n = rem & 127;
            int l = mat >> 1;
            const float* W = (mat & 1) ? (W2 + l * HDIM * HDIM) : (W1 + l * HDIM * HDIM);
            wtb[mat * HDIM * HDIM + n * HDIM + k] = f2bf(W[k * HDIM + n]);
        } else if (idx < 7 * HDIM * HDIM) {
            int j = idx - 6 * HDIM * HDIM;
            int n = j >> 7, k = j & 127;
            wtb[idx] = f2bf(hW1[k * HDIM + n]);
        } else if (idx < 7 * HDIM * HDIM + ODIM * HDIM) {
            int j = idx - 7 * HDIM * HDIM;
            int n = j >> 7, k = j & 127;   // n in [0,64)
            wtb[idx] = f2bf(hW2[k * ODIM + n]);
        } else if (idx < 7 * HDIM * HDIM + ODIM * HDIM + HDIM) {
            xb[(size_t)N_NODES * HDIM + (idx - 7 * HDIM * HDIM - ODIM * HDIM)] = 0;
        } else if (idx < 7 * HDIM * HDIM + ODIM * HDIM + 2 * HDIM) {
            xa2[(size_t)N_NODES * HDIM + (idx - 7 * HDIM * HDIM - ODIM * HDIM - HDIM)] = 0;
        }
    }
}

// ---- fused gather + mlp1: 64 nodes/block, 512 threads ----
// Gather is chunk-outer over 4 src-chunks so co-resident blocks sweep the same
// 3.2 MB chunk in near-lockstep (L2-resident); a stride-64B streaming prefetch
// of the next chunk's XCD-mate slice converts fills from random to sequential.
// Tail groups are masked to the zero sentinel row (no k_pad pass needed).

__global__ __launch_bounds__(512, 6) void k_gml(
    const unsigned short* __restrict__ x,
    const int* __restrict__ cnt,                 // [N][NCHUNK]
    const unsigned short* __restrict__ colidx,   // [N][NCHUNK][CCAP]
    const unsigned short* __restrict__ wt,       // [n][k] bf16
    const float* __restrict__ b1,
    unsigned short* __restrict__ hout,
    float* __restrict__ gstats)                  // [256]: 128 sum + 128 sumsq
{
    __shared__ float s_sum[HDIM], s_sq[HDIM];
    __shared__ __align__(16) unsigned short yb[64 * TPITCH];
    int tid = threadIdx.x;
    if (tid < HDIM) { s_sum[tid] = 0.f; s_sq[tid] = 0.f; }
    int nbase = blockIdx.x * 64;

    // ---- gather into registers (2 tasks/thread, chunk-outer) ----
    int gg[2], ss[2];
    float acc[2][8];
#pragma unroll
    for (int tt = 0; tt < 2; ++tt) {
        int t = tid + tt * 512;
        gg[tt] = nbase + (t >> 4);
        ss[tt] = (t & 15) * 8;
#pragma unroll
        for (int j = 0; j < 8; ++j) acc[tt][j] = 0.f;
        if (gg[tt] < N_NODES) {
            short8 v = *(const short8*)(x + (size_t)gg[tt] * HDIM + ss[tt]);
#pragma unroll
            for (int j = 0; j < 8; ++j) acc[tt][j] = bf2f((unsigned short)v[j]);
        }
    }

    int myslice = (blockIdx.x >> 3) % NSLICE;   // XCD-mate slice (b%8 round-robin)
    const float* xf = (const float*)x;
    // prefetch chunk 0 slice: one dword per thread at 64B stride covers 128 rows
    float pfv = xf[(size_t)(myslice * SLICE_ROWS) * (HDIM / 2) + tid * 16];

    for (int c = 0; c < NCHUNK; ++c) {
        float pfn = 0.f;
        if (c < NCHUNK - 1)
            pfn = xf[(size_t)((c + 1) * CROWS + myslice * SLICE_ROWS) * (HDIM / 2) + tid * 16];
#pragma unroll
        for (int tt = 0; tt < 2; ++tt) {
            int g = gg[tt], seg = ss[tt];
            if (g < N_NODES) {
                int deg = cnt[g * NCHUNK + c]; if (deg > CCAP) deg = CCAP;
                const unsigned short* bk = colidx + ((size_t)g * NCHUNK + c) * CCAP;
                for (int e = 0; e < deg; e += 8) {
                    ushort8 i0 = *(const ushort8*)(bk + e);
                    int rem = deg - e;
                    unsigned ix[8];
#pragma unroll
                    for (int j = 0; j < 8; ++j)
                        ix[j] = (j < rem) ? (unsigned)i0[j] : (unsigned)N_NODES;
                    short8 v0 = *(const short8*)(x + (size_t)ix[0] * HDIM + seg);
                    short8 v1 = *(const short8*)(x + (size_t)ix[1] * HDIM + seg);
                    short8 v2 = *(const short8*)(x + (size_t)ix[2] * HDIM + seg);
                    short8 v3 = *(const short8*)(x + (size_t)ix[3] * HDIM + seg);
                    short8 v4 = *(const short8*)(x + (size_t)ix[4] * HDIM + seg);
                    short8 v5 = *(const short8*)(x + (size_t)ix[5] * HDIM + seg);
                    short8 v6 = *(const short8*)(x + (size_t)ix[6] * HDIM + seg);
                    short8 v7 = *(const short8*)(x + (size_t)ix[7] * HDIM + seg);
#pragma unroll
                    for (int j = 0; j < 8; ++j)
                        acc[tt][j] += ((bf2f((unsigned short)v0[j]) + bf2f((unsigned short)v1[j])) +
                                       (bf2f((unsigned short)v2[j]) + bf2f((unsigned short)v3[j]))) +
                                      ((bf2f((unsigned short)v4[j]) + bf2f((unsigned short)v5[j])) +
                                       (bf2f((unsigned short)v6[j]) + bf2f((unsigned short)v7[j])));
                }
            }
        }
        asm volatile("" :: "v"(pfv));   // keep prefetch live; load overlapped gather
        pfv = pfn;
    }

#pragma unroll
    for (int tt = 0; tt < 2; ++tt) {
        short8 o;
#pragma unroll
        for (int j = 0; j < 8; ++j) o[j] = (short)f2bf(acc[tt][j]);
        int nl = (tid + tt * 512) >> 4;
        *(short8*)&yb[nl * TPITCH + ss[tt]] = o;
    }
    __syncthreads();

    // ---- MFMA: h = y @ W1 ----
    int wv = tid >> 6, lane = tid & 63;
    int m = lane & 15, quad = lane >> 4;
    int mrow = (wv & 3) * 16 + m;
    int ncol0 = (wv >> 2) * 64;

    short8 a[4];
#pragma unroll
    for (int kk = 0; kk < 4; ++kk)
        a[kk] = *(const short8*)&yb[mrow * TPITCH + kk * 32 + quad * 8];
    __syncthreads();   // all A-frag reads complete before C overwrites yb

    floatx4 acc4[4];
#pragma unroll
    for (int nt = 0; nt < 4; ++nt) {
        floatx4 c = {0.f, 0.f, 0.f, 0.f};
#pragma unroll
        for (int kk = 0; kk < 4; ++kk) {
            short8 b = *(const short8*)(wt + (ncol0 + nt * 16 + m) * HDIM + kk * 32 + quad * 8);
            c = __builtin_amdgcn_mfma_f32_16x16x32_bf16(a[kk], b, c, 0, 0, 0);
        }
        acc4[nt] = c;
    }

    // epilogue: +b1, stats, C -> LDS
    int lrow0 = (wv & 3) * 16 + quad * 4;
#pragma unroll
    for (int nt = 0; nt < 4; ++nt) {
        int n = ncol0 + nt * 16 + m;
        float bias = b1[n];
        float ssum = 0.f, ssq = 0.f;
#pragma unroll
        for (int r = 0; r < 4; ++r) {
            float val = acc4[nt][r] + bias;
            yb[(lrow0 + r) * TPITCH + n] = f2bf(val);
            if (nbase + lrow0 + r < N_NODES) { ssum += val; ssq += val * val; }
        }
        atomicAdd(&s_sum[n], ssum);
        atomicAdd(&s_sq[n], ssq);
    }
    __syncthreads();
    if (tid < HDIM) {
        // fold stats reduce into the epilogue: one device atomic per column
        atomicAdd(&gstats[tid], s_sum[tid]);
        atomicAdd(&gstats[HDIM + tid], s_sq[tid]);
    }
    // coalesced store: 8 threads/row, 32 B each (nt: don't pollute L2 chunk residency)
    int lrow = tid >> 3, off = (tid & 7) * 16;
    int grow = nbase + lrow;
    if (grow < N_NODES) {
        __builtin_nontemporal_store(*(const short8*)&yb[lrow * TPITCH + off],
                                    (short8*)(hout + (size_t)grow * HDIM + off));
        __builtin_nontemporal_store(*(const short8*)&yb[lrow * TPITCH + off + 8],
                                    (short8*)(hout + (size_t)grow * HDIM + off + 8));
    }
}

// ------- mlp2: x' = relu(BN(h) relu'd @ W2 + b2); LDS-staged C store -------

__global__ __launch_bounds__(256) void k_mlp2(
    const unsigned short* __restrict__ hin,
    const float* __restrict__ stats,
    const float* __restrict__ gamma,
    const float* __restrict__ beta,
    const unsigned short* __restrict__ wt,   // [n][k] bf16
    const float* __restrict__ b2,
    unsigned short* __restrict__ xout)
{
    __shared__ float s_scale[HDIM], s_shift[HDIM];
    __shared__ __align__(16) unsigned short tb[64 * TPITCH];
    int tid = threadIdx.x;
    if (tid < HDIM) {
        float mu = stats[tid] * (1.f / N_NODES);
        float var = stats[HDIM + tid] * (1.f / N_NODES) - mu * mu;
        float sc = gamma[tid] * rsqrtf(var + BN_EPS);
        s_scale[tid] = sc;
        s_shift[tid] = beta[tid] - mu * sc;
    }
    __syncthreads();

    int wv = tid >> 6, lane = tid & 63;
    int m = lane & 15, quad = lane >> 4;
    int row0 = blockIdx.x * 64 + wv * 16;
    int arow = row0 + m;

    short8 a[4];
    if (arow < N_NODES) {
#pragma unroll
        for (int kk = 0; kk < 4; ++kk) {
            short8 v = *(const short8*)(hin + (size_t)arow * HDIM + kk * 32 + quad * 8);
            int c0 = kk * 32 + quad * 8;
            short8 af;
#pragma unroll
            for (int j = 0; j < 8; ++j) {
                float f = fmaxf(bf2f((unsigned short)v[j]) * s_scale[c0 + j] + s_shift[c0 + j], 0.f);
                af[j] = (short)f2bf(f);
            }
            a[kk] = af;
        }
    } else {
#pragma unroll
        for (int kk = 0; kk < 4; ++kk) a[kk] = (short8)0;
    }

    floatx4 acc[8];
#pragma unroll
    for (int nt = 0; nt < 8; ++nt) {
        floatx4 c = {0.f, 0.f, 0.f, 0.f};
#pragma unroll
        for (int kk = 0; kk < 4; ++kk) {
            short8 b = *(const short8*)(wt + (nt * 16 + m) * HDIM + kk * 32 + quad * 8);
            c = __builtin_amdgcn_mfma_f32_16x16x32_bf16(a[kk], b, c, 0, 0, 0);
        }
        acc[nt] = c;
    }

    int lrow0 = wv * 16 + quad * 4;
#pragma unroll
    for (int nt = 0; nt < 8; ++nt) {
        int n = nt * 16 + m;
        float bias = b2[n];
#pragma unroll
        for (int r = 0; r < 4; ++r)
            tb[(lrow0 + r) * TPITCH + n] = f2bf(fmaxf(acc[nt][r] + bias, 0.f));
    }
    __syncthreads();
    int lrow = tid >> 2, off = (tid & 3) * 32;
    int grow = blockIdx.x * 64 + lrow;
    if (grow < N_NODES) {
#pragma unroll
        for (int i = 0; i < 4; ++i)
            *(short8*)(xout + (size_t)grow * HDIM + off + i * 8) =
                *(const short8*)&tb[lrow * TPITCH + off + i * 8];
    }
}

// ---------------- pool: g[gid] = sum of node rows (bf16 out) ----------------

__global__ __launch_bounds__(256) void k_pool(
    const unsigned short* __restrict__ xf,
    const int* __restrict__ batch,
    unsigned short* __restrict__ g)
{
    __shared__ float red[16][HDIM];
    int gid = blockIdx.x;
    int tid = threadIdx.x;

    int lo = 0, hi = N_NODES;
    while (lo < hi) { int mid = (lo + hi) >> 1; if (batch[mid] < gid) lo = mid + 1; else hi = mid; }
    int start = lo;
    int lo2 = start, hi2 = N_NODES;
    while (lo2 < hi2) { int mid = (lo2 + hi2) >> 1; if (batch[mid] < gid + 1) lo2 = mid + 1; else hi2 = mid; }
    int end = lo2;

    int tsub = tid & 15, rgrp = tid >> 4;
    int seg = tsub * 8;
    float acc[8] = {0.f, 0.f, 0.f, 0.f, 0.f, 0.f, 0.f, 0.f};
    for (int r = start + rgrp; r < end; r += 16) {
        short8 v = *(const short8*)(xf + (size_t)r * HDIM + seg);
#pragma unroll
        for (int j = 0; j < 8; ++j) acc[j] += bf2f((unsigned short)v[j]);
    }
#pragma unroll
    for (int j = 0; j < 8; ++j) red[rgrp][seg + j] = acc[j];
    __syncthreads();
    if (tid < HDIM) {
        float s = 0.f;
#pragma unroll
        for (int i = 0; i < 16; ++i) s += red[i][tid];
        g[gid * HDIM + tid] = f2bf(s);
    }
}

// ---------------- head: out = relu(g@hW1+b1) @ hW2 + b2 (block-local) -------

__global__ __launch_bounds__(256) void k_head(
    const unsigned short* __restrict__ g,
    const unsigned short* __restrict__ w1t,  // [128][128] bf16 [n][k]
    const float* __restrict__ b1,
    const unsigned short* __restrict__ w2t,  // [64][128] bf16 [n][k]
    const float* __restrict__ b2,
    float* __restrict__ out)
{
    __shared__ unsigned short tb[64 * HPITCH];
    int tid = threadIdx.x;
    int wv = tid >> 6, lane = tid & 63;
    int m = lane & 15, quad = lane >> 4;
    int row0 = blockIdx.x * 64 + wv * 16;

    short8 a[4];
#pragma unroll
    for (int kk = 0; kk < 4; ++kk)
        a[kk] = *(const short8*)(g + (size_t)(row0 + m) * HDIM + kk * 32 + quad * 8);

    // stage 1: t = relu(g @ W1 + b1), 64x128, staged to LDS
#pragma unroll
    for (int nt = 0; nt < 8; ++nt) {
        floatx4 c = {0.f, 0.f, 0.f, 0.f};
#pragma unroll
        for (int kk = 0; kk < 4; ++kk) {
            short8 b = *(const short8*)(w1t + (nt * 16 + m) * HDIM + kk * 32 + quad * 8);
            c = __builtin_amdgcn_mfma_f32_16x16x32_bf16(a[kk], b, c, 0, 0, 0);
        }
        int n = nt * 16 + m;
        float bias = b1[n];
#pragma unroll
        for (int r = 0; r < 4; ++r) {
            int lrow = wv * 16 + quad * 4 + r;
            tb[lrow * HPITCH + n] = f2bf(fmaxf(c[r] + bias, 0.f));
        }
    }
    __syncthreads();

    // stage 2: out = t @ W2 + b2, 64x64
    short8 a2[4];
#pragma unroll
    for (int kk = 0; kk < 4; ++kk)
        a2[kk] = *(const short8*)&tb[(wv * 16 + m) * HPITCH + kk * 32 + quad * 8];

#pragma unroll
    for (int nt = 0; nt < 4; ++nt) {
        floatx4 c = {0.f, 0.f, 0.f, 0.f};
#pragma unroll
        for (int kk = 0; kk < 4; ++kk) {
            short8 b = *(const short8*)(w2t + (nt * 16 + m) * HDIM + kk * 32 + quad * 8);
            c = __builtin_amdgcn_mfma_f32_16x16x32_bf16(a2[kk], b, c, 0, 0, 0);
        }
        int n = nt * 16 + m;
        float bias = b2[n];
#pragma unroll
        for (int r = 0; r < 4; ++r) {
            int row = row0 + quad * 4 + r;
            out[(size_t)row * ODIM + n] = c[r] + bias;
        }
    }
}

// ---------------- launch ----------------

extern "C" void kernel_launch(void* const* d_in, const int* in_sizes, int n_in,
                              void* d_out, int out_size, void* d_ws, size_t ws_size,
                              hipStream_t stream) {
    const float* x        = (const float*)d_in[0];
    const float* conv_W1  = (const float*)d_in[1];
    const float* conv_b1  = (const float*)d_in[2];
    const float* conv_g   = (const float*)d_in[3];
    const float* conv_be  = (const float*)d_in[4];
    const float* conv_W2  = (const float*)d_in[5];
    const float* conv_b2  = (const float*)d_in[6];
    const float* head_W1  = (const float*)d_in[7];
    const float* head_b1  = (const float*)d_in[8];
    const float* head_W2  = (const float*)d_in[9];
    const float* head_b2  = (const float*)d_in[10];
    const int*   edges    = (const int*)d_in[11];   // [0..E)=src, [E..2E)=dst
    const int*   batch    = (const int*)d_in[12];

    char* ws = (char*)d_ws;
    int*            cnt4   = (int*)(ws + 0);                    // 50000*4*4   =    800,000 B
    float*          stats  = (float*)(ws + 800000);             // 3*256*4     =      3,072 B
    unsigned short* colidx = (unsigned short*)(ws + 803072);    // 50000*4*24*2=  9,600,000 B
    unsigned short* wtb    = (unsigned short*)(ws + 10403072);  //                  245,760 B
    unsigned short* gbuf   = (unsigned short*)(ws + 10648832);  //                  131,072 B
    unsigned short* xa     = (unsigned short*)(ws + 10779904);  // (N+1) rows  = 12,800,256 B
    unsigned short* xb     = (unsigned short*)(ws + 23580160);  // 12,800,256 B -> 36,380,416 total
    (void)in_sizes; (void)n_in; (void)out_size; (void)ws_size;

    hipMemsetAsync(ws, 0, 803072, stream);                      // cnt4 + stats (atomic targets)

    k_prep<<<SCAT_BLK + CVT_BLK + CVTW_BLK, 256, 0, stream>>>(
        edges, edges + N_EDGES, cnt4, colidx, x, xa,
        conv_W1, conv_W2, head_W1, head_W2, wtb, xb);

    // x lives in xa for every layer; h in xb. Stats accumulate via k_gml atomics.
    for (int l = 0; l < NLAYER; ++l) {
        k_gml<<<GBLK, 512, 0, stream>>>(xa, cnt4, colidx,
                                        wtb + (2 * l) * HDIM * HDIM,
                                        conv_b1 + l * HDIM, xb, stats + l * 256);
        k_mlp2<<<NBLK, 256, 0, stream>>>(xb, stats + l * 256,
                                         conv_g + l * HDIM, conv_be + l * HDIM,
                                         wtb + (2 * l + 1) * HDIM * HDIM,
                                         conv_b2 + l * HDIM, xa);
    }

    k_pool<<<NGRAPH, 256, 0, stream>>>(xa, batch, gbuf);
    k_head<<<NGRAPH / 64, 256, 0, stream>>>(gbuf, wtb + 6 * HDIM * HDIM, head_b1,
                                            wtb + 7 * HDIM * HDIM, head_b2,
                                            (float*)d_out);
}